// Round 4
// baseline (582.607 us; speedup 1.0000x reference)
//
#include <hip/hip_runtime.h>
#include <hip/hip_bf16.h>
#include <math.h>

#define B_ 256
#define S_ 512
#define H_ 256
#define D_ 512

typedef __bf16 bf16;
typedef __bf16 bf16x8 __attribute__((ext_vector_type(8)));
typedef float  f32x4  __attribute__((ext_vector_type(4)));
typedef unsigned short u16x8 __attribute__((ext_vector_type(8)));
typedef unsigned short u16x4 __attribute__((ext_vector_type(4)));
typedef unsigned int   u32x4 __attribute__((ext_vector_type(4)));

#define MFMA(a, b, c) __builtin_amdgcn_mfma_f32_16x16x32_bf16((a), (b), (c), 0, 0, 0)

__device__ __forceinline__ int swz(int row, int kbyte) {
  return (row * 128 + kbyte) ^ ((row & 7) << 4);
}
__device__ __forceinline__ unsigned short bfbits(float f) {
  bf16 h = (bf16)f;
  union { bf16 b; unsigned short u; } c; c.b = h; return c.u;
}
__device__ __forceinline__ bf16x8 cvt8(const float* __restrict__ p) {
  f32x4 a = *(const f32x4*)p;
  f32x4 b = *(const f32x4*)(p + 4);
  bf16x8 r;
  r[0] = (bf16)a[0]; r[1] = (bf16)a[1]; r[2] = (bf16)a[2]; r[3] = (bf16)a[3];
  r[4] = (bf16)b[0]; r[5] = (bf16)b[1]; r[6] = (bf16)b[2]; r[7] = (bf16)b[3];
  return r;
}
__device__ __forceinline__ void gload16(const unsigned short* g, unsigned char* l) {
  __builtin_amdgcn_global_load_lds(
      (const __attribute__((address_space(1))) unsigned int*)g,
      (__attribute__((address_space(3))) unsigned int*)l, 16, 0, 0);
}

// ---------------------------------------------------------------------------
// Weight conversion (tiny, once).
// ---------------------------------------------------------------------------
__global__ __launch_bounds__(256) void k_convw(
    const float* __restrict__ kw, const float* __restrict__ qw,
    const float* __restrict__ vw, unsigned short* __restrict__ wc)
{
  const int r = blockIdx.x;
  const float* src = (r < 256) ? kw + (size_t)r * 512
                   : (r < 512) ? qw + (size_t)(r - 256) * 512
                               : vw + (size_t)(r - 512) * 512;
  const int c = threadIdx.x * 2;
  wc[(size_t)r * 512 + c]     = bfbits(src[c]);
  wc[(size_t)r * 512 + c + 1] = bfbits(src[c + 1]);
}

// ---------------------------------------------------------------------------
// Kernel 1: QKV projection. A-side: fp32 x staged with in-register cvt to
// bf16 (swizzled LDS). B-side: bf16 weights via global_load_lds (linear LDS).
// Single launch over all m; L3 absorbs the 6x x re-read (n-fastest order).
// ---------------------------------------------------------------------------
__global__ __launch_bounds__(256) void k_proj2(
    const float* __restrict__ x,
    const unsigned short* __restrict__ wc,
    const float* __restrict__ kbi, const float* __restrict__ qbi,
    const float* __restrict__ vbi,
    unsigned short* __restrict__ k_t, unsigned short* __restrict__ q_t,
    unsigned short* __restrict__ v_o, int nwg)
{
  __shared__ __align__(16) unsigned char sA[16384];  // 128 m x 64 k bf16 (swz)
  __shared__ __align__(16) unsigned char sB[16384];  // 128 n x 64 k bf16 (linear)

  const int o = blockIdx.x;
  const int cpx = nwg >> 3;
  const int a = (o & 7) * cpx + (o >> 3);            // bijective (nwg%8==0)
  const int mt = a / 6;
  const int nb = a - mt * 6;
  const int m0 = mt * 128;
  const int n0 = nb * 128;
  const int region = nb >> 1;
  const int h0 = (nb & 1) * 128;
  const float* __restrict__ Bi = (region == 0) ? kbi : (region == 1) ? qbi : vbi;

  const int tid = threadIdx.x;
  const int lane = tid & 63;
  const int wid = tid >> 6;
  const int wm = wid >> 1;
  const int wn = wid & 1;
  const int l15 = lane & 15;

  f32x4 acc[4][4];
#pragma unroll
  for (int i = 0; i < 4; ++i)
#pragma unroll
    for (int j = 0; j < 4; ++j) acc[i][j] = (f32x4){0.f, 0.f, 0.f, 0.f};

  const int lr = lane >> 3;
  const int lk = (lane & 7) << 3;

  for (int kt = 0; kt < 8; ++kt) {
    if (kt) __syncthreads();
    // A: fp32 -> bf16 reg-staged, swizzled
#pragma unroll
    for (int i = 0; i < 4; ++i) {
      int c = tid + i * 256;                         // 1024 chunks of 16B
      int row = c >> 3, kc = (c & 7) * 8;
      *(bf16x8*)(sA + swz(row, kc * 2)) =
          cvt8(x + (size_t)(m0 + row) * D_ + kt * 64 + kc);
    }
    // B: async global->LDS, linear
#pragma unroll
    for (int i = 0; i < 4; ++i) {
      const int chunk = wid * 4 + i;
      const int row = chunk * 8 + lr;
      gload16(wc + (size_t)(n0 + row) * 512 + kt * 64 + lk, sB + chunk * 1024);
    }
    __syncthreads();
#pragma unroll
    for (int ks = 0; ks < 2; ++ks) {
      const int kb2 = ks * 64 + ((lane >> 4) << 4);
      bf16x8 av[4], bv[4];
#pragma unroll
      for (int f = 0; f < 4; ++f)
        av[f] = *(const bf16x8*)(sA + swz(wm * 64 + f * 16 + l15, kb2));
#pragma unroll
      for (int f = 0; f < 4; ++f)
        bv[f] = *(const bf16x8*)(sB + (wn * 64 + f * 16 + l15) * 128 + kb2);
#pragma unroll
      for (int fm = 0; fm < 4; ++fm)
#pragma unroll
        for (int fn = 0; fn < 4; ++fn)
          acc[fm][fn] = MFMA(av[fm], bv[fn], acc[fm][fn]);
    }
  }

  const int b = m0 >> 9;
  const int sbase = m0 & 511;
  const int r4 = (lane >> 4) * 4;
#pragma unroll
  for (int fn = 0; fn < 4; ++fn) {
    const int hcol = h0 + wn * 64 + fn * 16 + l15;
    const float bias = Bi[hcol];
#pragma unroll
    for (int fm = 0; fm < 4; ++fm) {
      const int s = sbase + wm * 64 + fm * 16 + r4;
      if (region < 2) {
        unsigned short* dst = ((region == 0) ? k_t : q_t) +
                              (size_t)b * (H_ * S_) + (size_t)hcol * S_ + s;
        u16x4 ov;
#pragma unroll
        for (int j = 0; j < 4; ++j) ov[j] = bfbits(acc[fm][fn][j] + bias);
        *(u16x4*)dst = ov;
      } else {
#pragma unroll
        for (int j = 0; j < 4; ++j)
          v_o[(size_t)b * (S_ * H_) + (size_t)(s + j) * H_ + hcol] =
              bfbits(acc[fm][fn][j] + bias);
      }
    }
  }
}

// ---------------------------------------------------------------------------
// Kernel 2: fused scores+softmax+PV+bias+LN+GELU, register-resident P.
// 1 block (8 waves) per batch. Wave w owns g-slice [w*32, w*32+32) for ALL
// 256 h: acc1[16][2]. All operands load global->VGPR directly (no staging,
// no barriers until the LN epilogue). Column softmax = in-register + 2
// shfl_xor. P->B-fragment relayout = wave-local shuffles (src lane holds the
// needed j-quad: rq_src=(l16&1)*2(+1), fm=kb*2+(l16>>1)).
// ---------------------------------------------------------------------------
__global__ __launch_bounds__(512, 2) void k_attn(
    const unsigned short* __restrict__ k_t,
    const unsigned short* __restrict__ q_t,
    const unsigned short* __restrict__ v_o,
    const float* __restrict__ attn_bias,
    const float* __restrict__ lng, const float* __restrict__ lnb,
    unsigned short* __restrict__ act)
{
  __shared__ float lbuf[2][8][64];

  const int tid = threadIdx.x;
  const int lane = tid & 63;
  const int wg = tid >> 6;            // 0..7: g-slice
  const int b = blockIdx.x;
  const int l15 = lane & 15;
  const int l16 = lane >> 4;          // 0..3
  const int g0 = wg * 32;

  const unsigned short* __restrict__ Kb = k_t + (size_t)b * (H_ * S_);
  const unsigned short* __restrict__ Qb = q_t + (size_t)b * (H_ * S_);
  const unsigned short* __restrict__ Vb = v_o + (size_t)b * (S_ * H_);

  // ---- Phase 1: S[h, g-slice] = K . Q^T, direct global loads ----
  f32x4 acc1[16][2];
#pragma unroll
  for (int i = 0; i < 16; ++i) {
    acc1[i][0] = (f32x4){0.f, 0.f, 0.f, 0.f};
    acc1[i][1] = (f32x4){0.f, 0.f, 0.f, 0.f};
  }

  for (int kt = 0; kt < 8; ++kt) {
#pragma unroll
    for (int ks = 0; ks < 2; ++ks) {
      const int soff = kt * 64 + ks * 32 + l16 * 8;
      bf16x8 bv0 = *(const bf16x8*)(Qb + (size_t)(g0 + l15) * S_ + soff);
      bf16x8 bv1 = *(const bf16x8*)(Qb + (size_t)(g0 + 16 + l15) * S_ + soff);
#pragma unroll
      for (int fh = 0; fh < 2; ++fh) {
        bf16x8 av[8];
#pragma unroll
        for (int f = 0; f < 8; ++f)
          av[f] = *(const bf16x8*)(Kb + (size_t)((fh * 8 + f) * 16 + l15) * S_ + soff);
#pragma unroll
        for (int f = 0; f < 8; ++f) {
          acc1[fh * 8 + f][0] = MFMA(av[f], bv0, acc1[fh * 8 + f][0]);
          acc1[fh * 8 + f][1] = MFMA(av[f], bv1, acc1[fh * 8 + f][1]);
        }
      }
    }
  }

  // ---- column softmax over h, fully in-register ----
  float mx[2] = {-3.0e38f, -3.0e38f};
#pragma unroll
  for (int fm = 0; fm < 16; ++fm)
#pragma unroll
    for (int fn = 0; fn < 2; ++fn)
#pragma unroll
      for (int j = 0; j < 4; ++j) {
        acc1[fm][fn][j] *= 0.0625f;
        mx[fn] = fmaxf(mx[fn], acc1[fm][fn][j]);
      }
#pragma unroll
  for (int fn = 0; fn < 2; ++fn) {
    mx[fn] = fmaxf(mx[fn], __shfl_xor(mx[fn], 16));
    mx[fn] = fmaxf(mx[fn], __shfl_xor(mx[fn], 32));
  }
  float sm[2] = {0.f, 0.f};
#pragma unroll
  for (int fm = 0; fm < 16; ++fm)
#pragma unroll
    for (int fn = 0; fn < 2; ++fn)
#pragma unroll
      for (int j = 0; j < 4; ++j) {
        float p = __expf(acc1[fm][fn][j] - mx[fn]);
        acc1[fm][fn][j] = p;
        sm[fn] += p;
      }
  float gi[2];
#pragma unroll
  for (int fn = 0; fn < 2; ++fn) {
    sm[fn] += __shfl_xor(sm[fn], 16);
    sm[fn] += __shfl_xor(sm[fn], 32);
    gi[fn] = 1.0f / sm[fn];
  }

  // ---- P -> PV B-fragments, wave-local shuffles ----
  // bv[kb][fn] element e = P[kb*32 + l16*8 + e][g0 + fn*16 + l15]
  bf16x8 bvv[8][2];
  const int src0 = l15 + ((l16 & 1) << 5);
  const int src1 = src0 + 16;
  const bool hi = (l16 >> 1) != 0;
#pragma unroll
  for (int kb = 0; kb < 8; ++kb) {
#pragma unroll
    for (int fn = 0; fn < 2; ++fn) {
      const float gi_ = gi[fn];
      unsigned int A0 = bfbits(acc1[kb * 2][fn][0] * gi_) |
                        ((unsigned int)bfbits(acc1[kb * 2][fn][1] * gi_) << 16);
      unsigned int A1 = bfbits(acc1[kb * 2][fn][2] * gi_) |
                        ((unsigned int)bfbits(acc1[kb * 2][fn][3] * gi_) << 16);
      unsigned int B0 = bfbits(acc1[kb * 2 + 1][fn][0] * gi_) |
                        ((unsigned int)bfbits(acc1[kb * 2 + 1][fn][1] * gi_) << 16);
      unsigned int B1 = bfbits(acc1[kb * 2 + 1][fn][2] * gi_) |
                        ((unsigned int)bfbits(acc1[kb * 2 + 1][fn][3] * gi_) << 16);
      unsigned int t0 = (unsigned int)__shfl((int)A0, src0);
      unsigned int t1 = (unsigned int)__shfl((int)A1, src0);
      unsigned int t2 = (unsigned int)__shfl((int)A0, src1);
      unsigned int t3 = (unsigned int)__shfl((int)A1, src1);
      unsigned int u0 = (unsigned int)__shfl((int)B0, src0);
      unsigned int u1 = (unsigned int)__shfl((int)B1, src0);
      unsigned int u2 = (unsigned int)__shfl((int)B0, src1);
      unsigned int u3 = (unsigned int)__shfl((int)B1, src1);
      u32x4 w;
      w[0] = hi ? u0 : t0;
      w[1] = hi ? u1 : t1;
      w[2] = hi ? u2 : t2;
      w[3] = hi ? u3 : t3;
      union { u32x4 u; bf16x8 v; } cv;
      cv.u = w;
      bvv[kb][fn] = cv.v;
    }
  }

  // act aliases k_t: ensure ALL waves finished reading Kb/Qb before stores.
  __syncthreads();

  // ---- Phase 2: out[s, g-slice] = V . P + bias, LN, GELU ----
  const float lgm0 = lng[g0 + l15],      lbm0 = lnb[g0 + l15];
  const float lgm1 = lng[g0 + 16 + l15], lbm1 = lnb[g0 + 16 + l15];

  for (int ms = 0; ms < 8; ++ms) {
    const int s0 = ms * 64;
    f32x4 acc2[4][2];
#pragma unroll
    for (int i = 0; i < 4; ++i) {
      acc2[i][0] = (f32x4){0.f, 0.f, 0.f, 0.f};
      acc2[i][1] = (f32x4){0.f, 0.f, 0.f, 0.f};
    }
#pragma unroll
    for (int kb = 0; kb < 8; ++kb) {
      bf16x8 av[4];
#pragma unroll
      for (int f = 0; f < 4; ++f)
        av[f] = *(const bf16x8*)(
            Vb + (size_t)(s0 + f * 16 + l15) * H_ + kb * 32 + l16 * 8);
#pragma unroll
      for (int f = 0; f < 4; ++f) {
        acc2[f][0] = MFMA(av[f], bvv[kb][0], acc2[f][0]);
        acc2[f][1] = MFMA(av[f], bvv[kb][1], acc2[f][1]);
      }
    }

    // bias add + per-row partial sums (row s = s0 + f*16 + l16*4 + j)
#pragma unroll
    for (int f = 0; f < 4; ++f) {
#pragma unroll
      for (int j = 0; j < 4; ++j) {
        const int rloc = f * 16 + l16 * 4 + j;
        const int s = s0 + rloc;
        float v0 = acc2[f][0][j] + attn_bias[(size_t)s * H_ + g0 + l15];
        float v1 = acc2[f][1][j] + attn_bias[(size_t)s * H_ + g0 + 16 + l15];
        acc2[f][0][j] = v0;
        acc2[f][1][j] = v1;
        float ps = v0 + v1, psq = v0 * v0 + v1 * v1;
        ps += __shfl_xor(ps, 1);  psq += __shfl_xor(psq, 1);
        ps += __shfl_xor(ps, 2);  psq += __shfl_xor(psq, 2);
        ps += __shfl_xor(ps, 4);  psq += __shfl_xor(psq, 4);
        ps += __shfl_xor(ps, 8);  psq += __shfl_xor(psq, 8);
        if (l15 == 0) { lbuf[0][wg][rloc] = ps; lbuf[1][wg][rloc] = psq; }
      }
    }
    __syncthreads();
#pragma unroll
    for (int f = 0; f < 4; ++f) {
#pragma unroll
      for (int j = 0; j < 4; ++j) {
        const int rloc = f * 16 + l16 * 4 + j;
        const int s = s0 + rloc;
        float sum = 0.f, sq = 0.f;
#pragma unroll
        for (int w = 0; w < 8; ++w) { sum += lbuf[0][w][rloc]; sq += lbuf[1][w][rloc]; }
        float mu = sum * (1.f / H_);
        float var = sq * (1.f / H_) - mu * mu;
        float rstd = rsqrtf(var + 1e-5f);
        float x0 = (acc2[f][0][j] - mu) * rstd * lgm0 + lbm0;
        float x1 = (acc2[f][1][j] - mu) * rstd * lgm1 + lbm1;
        float y0 = 0.5f * x0 * (1.f + erff(x0 * 0.70710678118654752f));
        float y1 = 0.5f * x1 * (1.f + erff(x1 * 0.70710678118654752f));
        act[(size_t)b * (S_ * H_) + (size_t)s * H_ + g0 + l15] = bfbits(y0);
        act[(size_t)b * (S_ * H_) + (size_t)s * H_ + g0 + 16 + l15] = bfbits(y1);
      }
    }
    __syncthreads();
  }
}

// ---------------------------------------------------------------------------
// Kernel 3: final GEMM, split-K (unchanged).
// ---------------------------------------------------------------------------
__global__ __launch_bounds__(512) void k_final(
    const unsigned short* __restrict__ act,
    const float* __restrict__ ow,
    float* __restrict__ partial)
{
  __shared__ __align__(16) unsigned char sA[256 * 128];
  __shared__ __align__(16) unsigned char sB[64 * 128];

  const int tid = threadIdx.x;
  const int lane = tid & 63;
  const int wid = tid >> 6;
  const int wm = wid >> 1;
  const int wn = wid & 1;
  const int n0 = blockIdx.x * 64;
  const size_t k0 = (size_t)blockIdx.y * 4096;

  f32x4 acc[4][2];
#pragma unroll
  for (int i = 0; i < 4; ++i)
#pragma unroll
    for (int j = 0; j < 2; ++j) acc[i][j] = (f32x4){0.f, 0.f, 0.f, 0.f};

  for (int kt = 0; kt < 64; ++kt) {
    const size_t kb = k0 + kt * 64;
    __syncthreads();
#pragma unroll
    for (int i = 0; i < 4; ++i) {
      int c = tid + i * 512;
      int row = c >> 3, kc = (c & 7) * 8;
      *(u16x8*)(sA + swz(row, kc * 2)) =
          *(const u16x8*)(act + (size_t)row * 131072 + kb + kc);
    }
    {
      int row = tid >> 3, kc = (tid & 7) * 8;
      *(bf16x8*)(sB + swz(row, kc * 2)) =
          cvt8(ow + (size_t)(n0 + row) * 131072 + kb + kc);
    }
    __syncthreads();
#pragma unroll
    for (int ks = 0; ks < 2; ++ks) {
      const int kbyte = ks * 64 + (lane >> 4) * 16;
      bf16x8 av[4], bv[2];
#pragma unroll
      for (int f = 0; f < 4; ++f)
        av[f] = *(const bf16x8*)(sA + swz(wm * 64 + f * 16 + (lane & 15), kbyte));
#pragma unroll
      for (int f = 0; f < 2; ++f)
        bv[f] = *(const bf16x8*)(sB + swz(wn * 32 + f * 16 + (lane & 15), kbyte));
#pragma unroll
      for (int fm = 0; fm < 4; ++fm)
#pragma unroll
        for (int fn = 0; fn < 2; ++fn)
          acc[fm][fn] = MFMA(av[fm], bv[fn], acc[fm][fn]);
    }
  }

  float* __restrict__ P = partial + (size_t)blockIdx.y * (256 * 512);
  const int r4 = (lane >> 4) * 4;
#pragma unroll
  for (int fn = 0; fn < 2; ++fn) {
    int col = n0 + wn * 32 + fn * 16 + (lane & 15);
#pragma unroll
    for (int fm = 0; fm < 4; ++fm) {
      int mb = wm * 64 + fm * 16 + r4;
#pragma unroll
      for (int j = 0; j < 4; ++j)
        P[(size_t)(mb + j) * 512 + col] = acc[fm][fn][j];
    }
  }
}

__global__ __launch_bounds__(256) void k_reduce(
    const float* __restrict__ partial,
    const float* __restrict__ ob,
    float* __restrict__ out)
{
  const int i4 = blockIdx.x * 256 + threadIdx.x;
  f32x4 s = *(const f32x4*)(ob + ((i4 & 127) << 2));
#pragma unroll
  for (int ks = 0; ks < 32; ++ks)
    s += *(const f32x4*)(partial + (size_t)ks * 131072 + (size_t)i4 * 4);
  *(f32x4*)(out + (size_t)i4 * 4) = s;
}

// ---------------------------------------------------------------------------
extern "C" void kernel_launch(void* const* d_in, const int* in_sizes, int n_in,
                              void* d_out, int out_size, void* d_ws, size_t ws_size,
                              hipStream_t stream) {
  const float* x         = (const float*)d_in[0];
  const float* k_w       = (const float*)d_in[1];
  const float* k_b       = (const float*)d_in[2];
  const float* q_w       = (const float*)d_in[3];
  const float* q_b       = (const float*)d_in[4];
  const float* v_w       = (const float*)d_in[5];
  const float* v_b       = (const float*)d_in[6];
  const float* attn_bias = (const float*)d_in[7];
  const float* ln_g      = (const float*)d_in[8];
  const float* ln_b      = (const float*)d_in[9];
  const float* out_w     = (const float*)d_in[10];
  const float* out_b     = (const float*)d_in[11];
  float* out = (float*)d_out;

  char* ws = (char*)d_ws;
  // Layout:
  //   [0,64M)    k_t [B][H][S] bf16   (aliased by act in k_attn phase 2;
  //                                    per-block safe: block b reads k_t[b]
  //                                    only before its __syncthreads())
  //   [64,128M)  q_t [B][H][S] bf16   (aliased by partial in k_final)
  //   [128,192M) v_o [B][S][H] bf16
  //   [192M+)    wc  [768][512] bf16
  unsigned short* k_t = (unsigned short*)(ws);
  unsigned short* q_t = (unsigned short*)(ws + 67108864);
  unsigned short* v_o = (unsigned short*)(ws + 134217728);
  unsigned short* wc  = (unsigned short*)(ws + 201326592);
  unsigned short* act = k_t;
  float* partial      = (float*)(ws + 67108864);

  k_convw<<<dim3(768), dim3(256), 0, stream>>>(k_w, q_w, v_w, wc);

  const int nwg = 6144;  // 1024 m-tiles x 6 n-tiles, %8==0
  k_proj2<<<dim3(nwg), dim3(256), 0, stream>>>(
      x, wc, k_b, q_b, v_b, k_t, q_t, v_o, nwg);

  k_attn<<<dim3(256), dim3(512), 0, stream>>>(
      k_t, q_t, v_o, attn_bias, ln_g, ln_b, act);

  k_final<<<dim3(8, 32), dim3(512), 0, stream>>>(act, out_w, partial);
  k_reduce<<<dim3(128), dim3(256), 0, stream>>>(partial, out_b, out);
}

// Round 5
// 476.061 us; speedup vs baseline: 1.2238x; 1.2238x over previous
//
#include <hip/hip_runtime.h>
#include <hip/hip_bf16.h>
#include <math.h>

#define B_ 256
#define S_ 512
#define H_ 256
#define D_ 512

typedef __bf16 bf16;
typedef __bf16 bf16x8 __attribute__((ext_vector_type(8)));
typedef float  f32x4  __attribute__((ext_vector_type(4)));
typedef unsigned short u16x8 __attribute__((ext_vector_type(8)));
typedef unsigned short u16x4 __attribute__((ext_vector_type(4)));

#define MFMA(a, b, c) __builtin_amdgcn_mfma_f32_16x16x32_bf16((a), (b), (c), 0, 0, 0)

// 128B-row-stride tiles: XOR-swizzle 16B slot with row&7 (involution).
__device__ __forceinline__ int swz(int row, int kbyte) {
  return (row * 128 + kbyte) ^ ((row & 7) << 4);
}
__device__ __forceinline__ unsigned short bfbits(float f) {
  bf16 h = (bf16)f;
  union { bf16 b; unsigned short u; } c; c.b = h; return c.u;
}
__device__ __forceinline__ bf16x8 cvt8(const float* __restrict__ p) {
  f32x4 a = *(const f32x4*)p;
  f32x4 b = *(const f32x4*)(p + 4);
  bf16x8 r;
  r[0] = (bf16)a[0]; r[1] = (bf16)a[1]; r[2] = (bf16)a[2]; r[3] = (bf16)a[3];
  r[4] = (bf16)b[0]; r[5] = (bf16)b[1]; r[6] = (bf16)b[2]; r[7] = (bf16)b[3];
  return r;
}
__device__ __forceinline__ void gload16(const unsigned short* g, unsigned char* l) {
  __builtin_amdgcn_global_load_lds(
      (const __attribute__((address_space(1))) unsigned int*)g,
      (__attribute__((address_space(3))) unsigned int*)l, 16, 0, 0);
}

// ---------------------------------------------------------------------------
// Weight conversion (tiny, once).
// ---------------------------------------------------------------------------
__global__ __launch_bounds__(256) void k_convw(
    const float* __restrict__ kw, const float* __restrict__ qw,
    const float* __restrict__ vw, unsigned short* __restrict__ wc)
{
  const int r = blockIdx.x;
  const float* src = (r < 256) ? kw + (size_t)r * 512
                   : (r < 512) ? qw + (size_t)(r - 256) * 512
                               : vw + (size_t)(r - 512) * 512;
  const int c = threadIdx.x * 2;
  wc[(size_t)r * 512 + c]     = bfbits(src[c]);
  wc[(size_t)r * 512 + c + 1] = bfbits(src[c + 1]);
}

// ---------------------------------------------------------------------------
// Kernel 1: QKV projection (unchanged from round 4).
// ---------------------------------------------------------------------------
__global__ __launch_bounds__(256) void k_proj2(
    const float* __restrict__ x,
    const unsigned short* __restrict__ wc,
    const float* __restrict__ kbi, const float* __restrict__ qbi,
    const float* __restrict__ vbi,
    unsigned short* __restrict__ k_t, unsigned short* __restrict__ q_t,
    unsigned short* __restrict__ v_o, int nwg)
{
  __shared__ __align__(16) unsigned char sA[16384];
  __shared__ __align__(16) unsigned char sB[16384];

  const int o = blockIdx.x;
  const int cpx = nwg >> 3;
  const int a = (o & 7) * cpx + (o >> 3);
  const int mt = a / 6;
  const int nb = a - mt * 6;
  const int m0 = mt * 128;
  const int n0 = nb * 128;
  const int region = nb >> 1;
  const int h0 = (nb & 1) * 128;
  const float* __restrict__ Bi = (region == 0) ? kbi : (region == 1) ? qbi : vbi;

  const int tid = threadIdx.x;
  const int lane = tid & 63;
  const int wid = tid >> 6;
  const int wm = wid >> 1;
  const int wn = wid & 1;
  const int l15 = lane & 15;

  f32x4 acc[4][4];
#pragma unroll
  for (int i = 0; i < 4; ++i)
#pragma unroll
    for (int j = 0; j < 4; ++j) acc[i][j] = (f32x4){0.f, 0.f, 0.f, 0.f};

  const int lr = lane >> 3;
  const int lk = (lane & 7) << 3;

  for (int kt = 0; kt < 8; ++kt) {
    if (kt) __syncthreads();
#pragma unroll
    for (int i = 0; i < 4; ++i) {
      int c = tid + i * 256;
      int row = c >> 3, kc = (c & 7) * 8;
      *(bf16x8*)(sA + swz(row, kc * 2)) =
          cvt8(x + (size_t)(m0 + row) * D_ + kt * 64 + kc);
    }
#pragma unroll
    for (int i = 0; i < 4; ++i) {
      const int chunk = wid * 4 + i;
      const int row = chunk * 8 + lr;
      gload16(wc + (size_t)(n0 + row) * 512 + kt * 64 + lk, sB + chunk * 1024);
    }
    __syncthreads();
#pragma unroll
    for (int ks = 0; ks < 2; ++ks) {
      const int kb2 = ks * 64 + ((lane >> 4) << 4);
      bf16x8 av[4], bv[4];
#pragma unroll
      for (int f = 0; f < 4; ++f)
        av[f] = *(const bf16x8*)(sA + swz(wm * 64 + f * 16 + l15, kb2));
#pragma unroll
      for (int f = 0; f < 4; ++f)
        bv[f] = *(const bf16x8*)(sB + (wn * 64 + f * 16 + l15) * 128 + kb2);
#pragma unroll
      for (int fm = 0; fm < 4; ++fm)
#pragma unroll
        for (int fn = 0; fn < 4; ++fn)
          acc[fm][fn] = MFMA(av[fm], bv[fn], acc[fm][fn]);
    }
  }

  const int b = m0 >> 9;
  const int sbase = m0 & 511;
  const int r4 = (lane >> 4) * 4;
#pragma unroll
  for (int fn = 0; fn < 4; ++fn) {
    const int hcol = h0 + wn * 64 + fn * 16 + l15;
    const float bias = Bi[hcol];
#pragma unroll
    for (int fm = 0; fm < 4; ++fm) {
      const int s = sbase + wm * 64 + fm * 16 + r4;
      if (region < 2) {
        unsigned short* dst = ((region == 0) ? k_t : q_t) +
                              (size_t)b * (H_ * S_) + (size_t)hcol * S_ + s;
        u16x4 ov;
#pragma unroll
        for (int j = 0; j < 4; ++j) ov[j] = bfbits(acc[fm][fn][j] + bias);
        *(u16x4*)dst = ov;
      } else {
#pragma unroll
        for (int j = 0; j < 4; ++j)
          v_o[(size_t)b * (S_ * H_) + (size_t)(s + j) * H_ + hcol] =
              bfbits(acc[fm][fn][j] + bias);
      }
    }
  }
}

// ---------------------------------------------------------------------------
// Kernel 2 (REBUILT): fused scores+softmax+PV+bias+LN+GELU.
// 1 block per batch, 1024 threads (16 waves, 4 waves/SIMD via launch_bounds).
// Phase 1: S[h,g] 256x256 via wave tiles 64x64 (wh=h-quarter, wq=g-quarter);
//   K,Q staged per 64-s step via global_load_lds (pre-swizzled source).
// Softmax over h: in-reg + cross-wave LDS reduce (redm/reds).
// P[g][h] bf16 -> 128 KB swizzled LDS (read as PV B-operand).
// Phase 2: out[s,g] via wave tiles 64x64, 2 outer s-halves; V staged per
//   32-h chunk (16 KB). Epilogue: +attn_bias, LN over g, erf-GELU.
// LDS 144 KB -> 1 block/CU, 16 waves/CU.
// ---------------------------------------------------------------------------
__global__ __launch_bounds__(1024, 4) void k_attn(
    const unsigned short* __restrict__ k_t,
    const unsigned short* __restrict__ q_t,
    const unsigned short* __restrict__ v_o,
    const float* __restrict__ attn_bias,
    const float* __restrict__ lng, const float* __restrict__ lnb,
    unsigned short* __restrict__ act)
{
  __shared__ __align__(16) unsigned char sm[147456];
  unsigned char* sP = sm;                       // 128 KB P[256 g][256 h]
  unsigned char* sK = sm;                       // phase1: 32 KB K slice
  unsigned char* sQ = sm + 32768;               // phase1: 32 KB Q slice
  unsigned char* sV = sm + 131072;              // phase2: 16 KB V slice
  float* redm = (float*)(sm + 131072);          // [4][256]
  float* reds = (float*)(sm + 131072 + 4096);   // [4][256]
  float* lbuf = (float*)(sm + 131072);          // [2][4][256] (aliases sV)

  const int tid = threadIdx.x;
  const int lane = tid & 63;
  const int wid = tid >> 6;           // 0..15
  const int l15 = lane & 15;
  const int l16 = lane >> 4;          // 0..3
  const int b = blockIdx.x;
  const int wh = wid >> 2;            // 0..3: h-quarter (p1) / s-quarter (p2)
  const int wq = wid & 3;             // 0..3: g-quarter

  const unsigned short* __restrict__ Kb = k_t + (size_t)b * (H_ * S_);
  const unsigned short* __restrict__ Qb = q_t + (size_t)b * (H_ * S_);
  const unsigned short* __restrict__ Vb = v_o + (size_t)b * (S_ * H_);

  // ---- Phase 1: S = K . Q^T ----
  const int srow8 = lane >> 3;                // 0..7
  const int scol16 = (lane & 7) ^ srow8;      // pre-swizzled 16B column

  f32x4 acc1[4][4];
#pragma unroll
  for (int i = 0; i < 4; ++i)
#pragma unroll
    for (int j = 0; j < 4; ++j) acc1[i][j] = (f32x4){0.f, 0.f, 0.f, 0.f};

  for (int kt = 0; kt < 8; ++kt) {
    if (kt) __syncthreads();
#pragma unroll
    for (int i = 0; i < 2; ++i) {
      const int cb = wid * 2 + i;             // 0..31 (8 rows each)
      const int row = cb * 8 + srow8;         // 0..255
      gload16(Kb + (size_t)row * S_ + kt * 64 + scol16 * 8, sK + cb * 1024);
      gload16(Qb + (size_t)row * S_ + kt * 64 + scol16 * 8, sQ + cb * 1024);
    }
    __syncthreads();
#pragma unroll
    for (int ks = 0; ks < 2; ++ks) {
      const int kb2 = ks * 64 + l16 * 16;
      bf16x8 av[4], bv[4];
#pragma unroll
      for (int f = 0; f < 4; ++f)
        av[f] = *(const bf16x8*)(sK + swz(wh * 64 + f * 16 + l15, kb2));
#pragma unroll
      for (int f = 0; f < 4; ++f)
        bv[f] = *(const bf16x8*)(sQ + swz(wq * 64 + f * 16 + l15, kb2));
#pragma unroll
      for (int fm = 0; fm < 4; ++fm)
#pragma unroll
        for (int fn = 0; fn < 4; ++fn)
          acc1[fm][fn] = MFMA(av[fm], bv[fn], acc1[fm][fn]);
    }
  }

  // ---- column softmax over h (4 wh-waves share a column) ----
  float cmax[4] = {-3.0e38f, -3.0e38f, -3.0e38f, -3.0e38f};
#pragma unroll
  for (int fm = 0; fm < 4; ++fm)
#pragma unroll
    for (int fn = 0; fn < 4; ++fn)
#pragma unroll
      for (int j = 0; j < 4; ++j) {
        acc1[fm][fn][j] *= 0.0625f;          // scale 256^-0.5
        cmax[fn] = fmaxf(cmax[fn], acc1[fm][fn][j]);
      }
#pragma unroll
  for (int fn = 0; fn < 4; ++fn) {
    cmax[fn] = fmaxf(cmax[fn], __shfl_xor(cmax[fn], 16));
    cmax[fn] = fmaxf(cmax[fn], __shfl_xor(cmax[fn], 32));
  }
  if (lane < 16) {
#pragma unroll
    for (int fn = 0; fn < 4; ++fn)
      redm[wh * 256 + wq * 64 + fn * 16 + lane] = cmax[fn];
  }
  __syncthreads();
  float gmax[4];
#pragma unroll
  for (int fn = 0; fn < 4; ++fn) {
    const int c = wq * 64 + fn * 16 + l15;
    gmax[fn] = fmaxf(fmaxf(redm[c], redm[256 + c]),
                     fmaxf(redm[512 + c], redm[768 + c]));
  }
  float csum[4] = {0.f, 0.f, 0.f, 0.f};
#pragma unroll
  for (int fm = 0; fm < 4; ++fm)
#pragma unroll
    for (int fn = 0; fn < 4; ++fn)
#pragma unroll
      for (int j = 0; j < 4; ++j) {
        float p = __expf(acc1[fm][fn][j] - gmax[fn]);
        acc1[fm][fn][j] = p;
        csum[fn] += p;
      }
#pragma unroll
  for (int fn = 0; fn < 4; ++fn) {
    csum[fn] += __shfl_xor(csum[fn], 16);
    csum[fn] += __shfl_xor(csum[fn], 32);
  }
  if (lane < 16) {
#pragma unroll
    for (int fn = 0; fn < 4; ++fn)
      reds[wh * 256 + wq * 64 + fn * 16 + lane] = csum[fn];
  }
  __syncthreads();
  float gi[4];
#pragma unroll
  for (int fn = 0; fn < 4; ++fn) {
    const int c = wq * 64 + fn * 16 + l15;
    gi[fn] = 1.0f / (reds[c] + reds[256 + c] + reds[512 + c] + reds[768 + c]);
  }

  // ---- write P[g][h] bf16, swizzled. Safe: all sK/sQ reads finished
  // before the first softmax barrier; red arrays live outside sP. ----
#pragma unroll
  for (int fn = 0; fn < 4; ++fn) {
    const int g = wq * 64 + fn * 16 + l15;
#pragma unroll
    for (int fm = 0; fm < 4; ++fm) {
      const int h0 = wh * 64 + fm * 16 + l16 * 4;
      u16x4 pv;
#pragma unroll
      for (int j = 0; j < 4; ++j) pv[j] = bfbits(acc1[fm][fn][j] * gi[fn]);
      *(u16x4*)(sP + ((g * 512 + h0 * 2) ^ ((g & 7) << 4))) = pv;
    }
  }

  // ---- Phase 2: out = V . P^T, two 256-s halves ----
  const int vrow = tid >> 2;                        // 0..255
  const int vcol16 = (tid & 3) ^ ((vrow >> 1) & 3); // pre-swizzled 16B col

  for (int so = 0; so < 2; ++so) {
    f32x4 acc2[4][4];
#pragma unroll
    for (int i = 0; i < 4; ++i)
#pragma unroll
      for (int j = 0; j < 4; ++j) acc2[i][j] = (f32x4){0.f, 0.f, 0.f, 0.f};

    for (int kh = 0; kh < 8; ++kh) {                // h chunks of 32
      __syncthreads();                              // prev sV/lbuf reads done
      gload16(Vb + (size_t)(so * 256 + vrow) * H_ + kh * 32 + vcol16 * 8,
              sV + wid * 1024);
      __syncthreads();
      bf16x8 av[4], bv[4];
#pragma unroll
      for (int f = 0; f < 4; ++f) {
        const int rl = wh * 64 + f * 16 + l15;
        av[f] = *(const bf16x8*)(sV + rl * 64 + ((l16 ^ ((rl >> 1) & 3)) << 4));
      }
#pragma unroll
      for (int fn = 0; fn < 4; ++fn) {
        const int g = wq * 64 + fn * 16 + l15;
        bv[fn] = *(const bf16x8*)(
            sP + ((g * 512 + kh * 64 + l16 * 16) ^ ((g & 7) << 4)));
      }
#pragma unroll
      for (int f = 0; f < 4; ++f)
#pragma unroll
        for (int fn = 0; fn < 4; ++fn)
          acc2[f][fn] = MFMA(av[f], bv[fn], acc2[f][fn]);
    }
    __syncthreads();                                // sV reads done (lbuf alias)

    // epilogue: +bias, LN over g (cross-wave via lbuf), GELU, store
#pragma unroll
    for (int f = 0; f < 4; ++f) {
#pragma unroll
      for (int j = 0; j < 4; ++j) {
        const int rloc = wh * 64 + f * 16 + l16 * 4 + j;  // 0..255
        const int s = so * 256 + rloc;
        float ps = 0.f, psq = 0.f;
#pragma unroll
        for (int fn = 0; fn < 4; ++fn) {
          const int g = wq * 64 + fn * 16 + l15;
          float vv = acc2[f][fn][j] + attn_bias[(size_t)s * H_ + g];
          acc2[f][fn][j] = vv;
          ps += vv; psq += vv * vv;
        }
        ps += __shfl_xor(ps, 1);  psq += __shfl_xor(psq, 1);
        ps += __shfl_xor(ps, 2);  psq += __shfl_xor(psq, 2);
        ps += __shfl_xor(ps, 4);  psq += __shfl_xor(psq, 4);
        ps += __shfl_xor(ps, 8);  psq += __shfl_xor(psq, 8);
        if (l15 == 0) {
          lbuf[wq * 256 + rloc] = ps;
          lbuf[1024 + wq * 256 + rloc] = psq;
        }
      }
    }
    __syncthreads();
#pragma unroll
    for (int f = 0; f < 4; ++f) {
#pragma unroll
      for (int j = 0; j < 4; ++j) {
        const int rloc = wh * 64 + f * 16 + l16 * 4 + j;
        const int s = so * 256 + rloc;
        float sum = lbuf[rloc] + lbuf[256 + rloc] +
                    lbuf[512 + rloc] + lbuf[768 + rloc];
        float sq  = lbuf[1024 + rloc] + lbuf[1280 + rloc] +
                    lbuf[1536 + rloc] + lbuf[1792 + rloc];
        float mu = sum * (1.f / H_);
        float var = sq * (1.f / H_) - mu * mu;
        float rstd = rsqrtf(var + 1e-5f);
#pragma unroll
        for (int fn = 0; fn < 4; ++fn) {
          const int g = wq * 64 + fn * 16 + l15;
          float xv = (acc2[f][fn][j] - mu) * rstd * lng[g] + lnb[g];
          float y = 0.5f * xv * (1.f + erff(xv * 0.70710678118654752f));
          act[(size_t)b * (S_ * H_) + (size_t)s * H_ + g] = bfbits(y);
        }
      }
    }
  }
}

// ---------------------------------------------------------------------------
// Kernel 3: final GEMM, split-K (unchanged).
// ---------------------------------------------------------------------------
__global__ __launch_bounds__(512) void k_final(
    const unsigned short* __restrict__ act,
    const float* __restrict__ ow,
    float* __restrict__ partial)
{
  __shared__ __align__(16) unsigned char sA[256 * 128];
  __shared__ __align__(16) unsigned char sB[64 * 128];

  const int tid = threadIdx.x;
  const int lane = tid & 63;
  const int wid = tid >> 6;
  const int wm = wid >> 1;
  const int wn = wid & 1;
  const int n0 = blockIdx.x * 64;
  const size_t k0 = (size_t)blockIdx.y * 4096;

  f32x4 acc[4][2];
#pragma unroll
  for (int i = 0; i < 4; ++i)
#pragma unroll
    for (int j = 0; j < 2; ++j) acc[i][j] = (f32x4){0.f, 0.f, 0.f, 0.f};

  for (int kt = 0; kt < 64; ++kt) {
    const size_t kb = k0 + kt * 64;
    __syncthreads();
#pragma unroll
    for (int i = 0; i < 4; ++i) {
      int c = tid + i * 512;
      int row = c >> 3, kc = (c & 7) * 8;
      *(u16x8*)(sA + swz(row, kc * 2)) =
          *(const u16x8*)(act + (size_t)row * 131072 + kb + kc);
    }
    {
      int row = tid >> 3, kc = (tid & 7) * 8;
      *(bf16x8*)(sB + swz(row, kc * 2)) =
          cvt8(ow + (size_t)(n0 + row) * 131072 + kb + kc);
    }
    __syncthreads();
#pragma unroll
    for (int ks = 0; ks < 2; ++ks) {
      const int kbyte = ks * 64 + (lane >> 4) * 16;
      bf16x8 av[4], bv[2];
#pragma unroll
      for (int f = 0; f < 4; ++f)
        av[f] = *(const bf16x8*)(sA + swz(wm * 64 + f * 16 + (lane & 15), kbyte));
#pragma unroll
      for (int f = 0; f < 2; ++f)
        bv[f] = *(const bf16x8*)(sB + swz(wn * 32 + f * 16 + (lane & 15), kbyte));
#pragma unroll
      for (int fm = 0; fm < 4; ++fm)
#pragma unroll
        for (int fn = 0; fn < 2; ++fn)
          acc[fm][fn] = MFMA(av[fm], bv[fn], acc[fm][fn]);
    }
  }

  float* __restrict__ P = partial + (size_t)blockIdx.y * (256 * 512);
  const int r4 = (lane >> 4) * 4;
#pragma unroll
  for (int fn = 0; fn < 2; ++fn) {
    int col = n0 + wn * 32 + fn * 16 + (lane & 15);
#pragma unroll
    for (int fm = 0; fm < 4; ++fm) {
      int mb = wm * 64 + fm * 16 + r4;
#pragma unroll
      for (int j = 0; j < 4; ++j)
        P[(size_t)(mb + j) * 512 + col] = acc[fm][fn][j];
    }
  }
}

__global__ __launch_bounds__(256) void k_reduce(
    const float* __restrict__ partial,
    const float* __restrict__ ob,
    float* __restrict__ out)
{
  const int i4 = blockIdx.x * 256 + threadIdx.x;
  f32x4 s = *(const f32x4*)(ob + ((i4 & 127) << 2));
#pragma unroll
  for (int ks = 0; ks < 32; ++ks)
    s += *(const f32x4*)(partial + (size_t)ks * 131072 + (size_t)i4 * 4);
  *(f32x4*)(out + (size_t)i4 * 4) = s;
}

// ---------------------------------------------------------------------------
extern "C" void kernel_launch(void* const* d_in, const int* in_sizes, int n_in,
                              void* d_out, int out_size, void* d_ws, size_t ws_size,
                              hipStream_t stream) {
  const float* x         = (const float*)d_in[0];
  const float* k_w       = (const float*)d_in[1];
  const float* k_b       = (const float*)d_in[2];
  const float* q_w       = (const float*)d_in[3];
  const float* q_b       = (const float*)d_in[4];
  const float* v_w       = (const float*)d_in[5];
  const float* v_b       = (const float*)d_in[6];
  const float* attn_bias = (const float*)d_in[7];
  const float* ln_g      = (const float*)d_in[8];
  const float* ln_b      = (const float*)d_in[9];
  const float* out_w     = (const float*)d_in[10];
  const float* out_b     = (const float*)d_in[11];
  float* out = (float*)d_out;

  char* ws = (char*)d_ws;
  // Layout:
  //   [0,64M)    k_t [B][H][S] bf16  (aliased by act in k_attn phase 2;
  //                                   per-block safe: block b's k_t reads all
  //                                   precede its act writes via barriers)
  //   [64,128M)  q_t [B][H][S] bf16  (aliased by partial in k_final)
  //   [128,192M) v_o [B][S][H] bf16
  //   [192M+)    wc  [768][512] bf16
  unsigned short* k_t = (unsigned short*)(ws);
  unsigned short* q_t = (unsigned short*)(ws + 67108864);
  unsigned short* v_o = (unsigned short*)(ws + 134217728);
  unsigned short* wc  = (unsigned short*)(ws + 201326592);
  unsigned short* act = k_t;
  float* partial      = (float*)(ws + 67108864);

  k_convw<<<dim3(768), dim3(256), 0, stream>>>(k_w, q_w, v_w, wc);

  const int nwg = 6144;
  k_proj2<<<dim3(nwg), dim3(256), 0, stream>>>(
      x, wc, k_b, q_b, v_b, k_t, q_t, v_o, nwg);

  k_attn<<<dim3(256), dim3(1024), 0, stream>>>(
      k_t, q_t, v_o, attn_bias, ln_g, ln_b, act);

  k_final<<<dim3(8, 32), dim3(512), 0, stream>>>(act, out_w, partial);
  k_reduce<<<dim3(128), dim3(256), 0, stream>>>(partial, out_b, out);
}